// Round 3
// baseline (140.860 us; speedup 1.0000x reference)
//
#include <hip/hip_runtime.h>
#include <hip/hip_bf16.h>
#include <cstdint>

#define BATCH  8192
#define INDIM  1024   // K
#define OUTDIM 2048   // N

typedef float  f32x4   __attribute__((ext_vector_type(4)));
typedef float  f32x16  __attribute__((ext_vector_type(16)));
typedef __bf16 bf16x8  __attribute__((ext_vector_type(8)));
typedef unsigned short u16x4 __attribute__((ext_vector_type(4)));
typedef unsigned short u16x8 __attribute__((ext_vector_type(8)));

__device__ __forceinline__ uint16_t f2b(float f) {
    __hip_bfloat16 h = __float2bfloat16(f);
    return __builtin_bit_cast(uint16_t, h);
}

// async global->LDS, 16B per lane. LDS dest is wave-uniform base + lane*16.
__device__ __forceinline__ void async_copy16(const void* g, void* l) {
    __builtin_amdgcn_global_load_lds(
        (__attribute__((address_space(1))) void*)(g),
        (__attribute__((address_space(3))) void*)(l),
        16, 0, 0);
}

// ---------------- merged prep -----------------------------------------------
// blocks 0..63   : P-part. Block owns 32 o-columns over full K.
//                  fp32 [K][O] -> Pt bf16 [O][K] + psq (no atomics, no zeroing).
// blocks 64..2111: x-part. 4 rows each: fp32 [B][K] -> x bf16 + xsq.
__global__ __launch_bounds__(256) void prep_all(const float* __restrict__ x,
                                                const float* __restrict__ P,
                                                uint16_t* __restrict__ xbf,
                                                uint16_t* __restrict__ ptbf,
                                                float* __restrict__ xsq,
                                                float* __restrict__ psq) {
    const int bid = blockIdx.x;
    if (bid < 64) {
        __shared__ float tile[64][33];
        __shared__ float psums[32];
        const int tid = threadIdx.x;
        const int o0  = bid * 32;
        // load layout: kk = k-row within half-tile, oq = float4 column group
        const int kk = tid >> 3;          // 0..31
        const int oq = tid & 7;           // 0..7
        // store layout: so = o column, skc = base k within tile
        const int so  = tid >> 3;         // 0..31
        const int skc = (tid & 7) * 8;    // 0..56
        float a4[4] = {0.f, 0.f, 0.f, 0.f};
        if (tid < 32) psums[tid] = 0.f;
        for (int k0 = 0; k0 < INDIM; k0 += 64) {
            __syncthreads();   // tile reuse guard (first iter: covers psums init)
#pragma unroll
            for (int r = 0; r < 2; ++r) {
                const int k = r * 32 + kk;
                const float4 v = *(const float4*)(P + (size_t)(k0 + k) * OUTDIM + o0 + oq * 4);
                tile[k][oq * 4 + 0] = v.x;
                tile[k][oq * 4 + 1] = v.y;
                tile[k][oq * 4 + 2] = v.z;
                tile[k][oq * 4 + 3] = v.w;
                a4[0] += v.x * v.x; a4[1] += v.y * v.y;
                a4[2] += v.z * v.z; a4[3] += v.w * v.w;
            }
            __syncthreads();
            u16x8 w;
#pragma unroll
            for (int j = 0; j < 8; ++j) w[j] = f2b(tile[skc + j][so]);
            *(u16x8*)(ptbf + (size_t)(o0 + so) * INDIM + k0 + skc) = w;
        }
#pragma unroll
        for (int e = 0; e < 4; ++e) atomicAdd(&psums[oq * 4 + e], a4[e]);
        __syncthreads();
        if (tid < 32) psq[o0 + tid] = psums[tid];
    } else {
        const int wave = threadIdx.x >> 6;
        const int lane = threadIdx.x & 63;
        const int row  = (bid - 64) * 4 + wave;
        const f32x4* src = (const f32x4*)(x + (size_t)row * INDIM);
        u16x4* dst = (u16x4*)(xbf + (size_t)row * INDIM);
        float s = 0.f;
#pragma unroll
        for (int w = 0; w < 4; ++w) {
            const f32x4 v = src[lane + w * 64];
            s += v.x * v.x + v.y * v.y + v.z * v.z + v.w * v.w;
            u16x4 o;
            o.x = f2b(v.x); o.y = f2b(v.y); o.z = f2b(v.z); o.w = f2b(v.w);
            dst[lane + w * 64] = o;
        }
#pragma unroll
        for (int off = 32; off > 0; off >>= 1) s += __shfl_down(s, off);
        if (lane == 0) xsq[row] = s;
    }
}

// ---------------- main GEMM + epilogue --------------------------------------
// C[m][n] = 2 * sum_k A[m][k] * Bt[n][k] - xsq[m] - psq[n]
// Tile 128x128, BK=64, 4 waves (2x2); each wave 64x64 via 2x2 frags of
// mfma_f32_32x32x16_bf16 (4 K-steps of 16 per LDS tile).
// LDS chunks XOR-swizzled: slot (r,c) holds global chunk c ^ (r&7).
#define TM 128
#define TN 128
#define BK 64

__global__ __launch_bounds__(256) void gemm_ep(const uint16_t* __restrict__ xbf,
                                               const uint16_t* __restrict__ ptbf,
                                               const float* __restrict__ xsq,
                                               const float* __restrict__ psq,
                                               float* __restrict__ out) {
    __shared__ __align__(16) uint16_t As[TM * BK];
    __shared__ __align__(16) uint16_t Bs[TN * BK];

    const int tid  = threadIdx.x;
    const int m0   = blockIdx.x * TM;   // 64 blocks
    const int n0   = blockIdx.y * TN;   // 16 blocks
    const int wave = tid >> 6;
    const int lane = tid & 63;
    const int wm   = (wave >> 1) * 64;
    const int wn   = (wave & 1) * 64;
    const int l31  = lane & 31;
    const int half = lane >> 5;
    const int sw   = l31 & 7;           // fragment-row swizzle key

    f32x16 acc[2][2];
#pragma unroll
    for (int i = 0; i < 2; ++i)
#pragma unroll
        for (int j = 0; j < 2; ++j)
#pragma unroll
            for (int e = 0; e < 16; ++e) acc[i][j][e] = 0.f;

    for (int kb = 0; kb < INDIM; kb += BK) {
        // stage A (128x64) and B (128x64); lane sources the XOR'd chunk so
        // slot (r, cs) holds global chunk cs ^ (r&7)
#pragma unroll
        for (int t = 0; t < 4; ++t) {
            const int id = t * 256 + tid;       // slot id 0..1023
            const int r  = id >> 3;             // tile row
            const int cs = id & 7;              // slot chunk
            const int cg = cs ^ (r & 7);        // global chunk
            async_copy16(xbf  + (size_t)(m0 + r) * INDIM + kb + cg * 8, As + id * 8);
            async_copy16(ptbf + (size_t)(n0 + r) * INDIM + kb + cg * 8, Bs + id * 8);
        }
        __syncthreads();

#pragma unroll
        for (int ks = 0; ks < 4; ++ks) {        // four K=16 steps
            const int c = ks * 2 + half;        // wanted chunk (8 bf16)
            bf16x8 a[2], b[2];
#pragma unroll
            for (int i = 0; i < 2; ++i)
                a[i] = *(const bf16x8*)(As + (wm + i * 32 + l31) * BK + (c ^ sw) * 8);
#pragma unroll
            for (int j = 0; j < 2; ++j)
                b[j] = *(const bf16x8*)(Bs + (wn + j * 32 + l31) * BK + (c ^ sw) * 8);
#pragma unroll
            for (int i = 0; i < 2; ++i)
#pragma unroll
                for (int j = 0; j < 2; ++j)
                    acc[i][j] = __builtin_amdgcn_mfma_f32_32x32x16_bf16(a[i], b[j], acc[i][j], 0, 0, 0);
        }
        __syncthreads();
    }

    // epilogue: C/D layout col = lane&31, row = (reg&3) + 8*(reg>>2) + 4*half
    const float* xsq_w = xsq + m0 + wm;
    const float* psq_w = psq + n0 + wn;
    float ps[2];
#pragma unroll
    for (int j = 0; j < 2; ++j) ps[j] = psq_w[j * 32 + l31];
#pragma unroll
    for (int i = 0; i < 2; ++i) {
#pragma unroll
        for (int rg = 0; rg < 16; ++rg) {
            const int rloc = (rg & 3) + 8 * (rg >> 2) + 4 * half;
            const float xs = xsq_w[i * 32 + rloc];
            float* orow = out + (size_t)(m0 + wm + i * 32 + rloc) * OUTDIM + n0 + wn + l31;
#pragma unroll
            for (int j = 0; j < 2; ++j)
                orow[j * 32] = 2.f * acc[i][j][rg] - xs - ps[j];
        }
    }
}

// ---------------- fallback (only if workspace is too small) -----------------
__global__ void fallback_kernel(const float* __restrict__ x,
                                const float* __restrict__ P,
                                float* __restrict__ out) {
    const int o = blockIdx.x * blockDim.x + threadIdx.x;
    const int b = blockIdx.y;
    float cr = 0.f, xq = 0.f, pq = 0.f;
    for (int i = 0; i < INDIM; ++i) {
        const float xv = x[(size_t)b * INDIM + i];
        const float pv = P[(size_t)i * OUTDIM + o];
        cr += xv * pv; xq += xv * xv; pq += pv * pv;
    }
    out[(size_t)b * OUTDIM + o] = 2.f * cr - xq - pq;
}

extern "C" void kernel_launch(void* const* d_in, const int* in_sizes, int n_in,
                              void* d_out, int out_size, void* d_ws, size_t ws_size,
                              hipStream_t stream) {
    (void)in_sizes; (void)n_in; (void)out_size;
    const float* x = (const float*)d_in[0];
    const float* P = (const float*)d_in[1];
    float* out = (float*)d_out;

    const size_t xbf_bytes = (size_t)BATCH * INDIM * 2;    // 16 MB
    const size_t pt_bytes  = (size_t)OUTDIM * INDIM * 2;   // 4 MB
    const size_t xsq_bytes = (size_t)BATCH * 4;
    const size_t psq_bytes = (size_t)OUTDIM * 4;
    const size_t need = xbf_bytes + pt_bytes + xsq_bytes + psq_bytes;

    if (ws_size < need) {
        fallback_kernel<<<dim3(OUTDIM / 256, BATCH), 256, 0, stream>>>(x, P, out);
        return;
    }

    uint16_t* xbf  = (uint16_t*)d_ws;
    uint16_t* ptbf = (uint16_t*)((char*)d_ws + xbf_bytes);
    float*    xsq  = (float*)((char*)d_ws + xbf_bytes + pt_bytes);
    float*    psq  = xsq + BATCH;

    prep_all<<<64 + BATCH / 4, 256, 0, stream>>>(x, P, xbf, ptbf, xsq, psq);
    gemm_ep<<<dim3(BATCH / TM, OUTDIM / TN), 256, 0, stream>>>(xbf, ptbf, xsq, psq, out);
}